// Round 2
// baseline (1603.495 us; speedup 1.0000x reference)
//
#include <hip/hip_runtime.h>
#include <cstdint>

// Instant-NGP hash-grid encoder, D=3, L=16, C=2, H=16, PS=2, T=2^19.
// Round-4: force-pin the gather cluster + non-temporal streaming.
//   Evidence r3: sched_barrier(0) alone left VGPR_Count at 56 => loads were
//   sunk to consumers at IR level (barrier is IntrNoMem; IR sinking ignores
//   it). Fix: per-load asm volatile("" :: "v"(x)) keep-alives give every
//   load an immediate opaque use (defeats IR sinking, forces 64 dwords
//   live) + sched_barrier(0) stops MIR re-hoisting of the combine.
//   Proof-of-pin signal: VGPR_Count must jump to >=110.
//   FETCH_SIZE 794MB vs 82MB compulsory => streaming in/out evicts the
//   4.19MB/level table from 4MB L2. All streaming traffic (inputs, ws,
//   out) is now nontemporal so table lines keep L2 residency.
//   Transpose: 256-pt tile, 8 pinned float4 loads/thread (depth vs ~900cy
//   HBM latency; was 1.55 TB/s for a 536MB shuffle), NT both sides.
// NUMERICS: pos = x01*scale + 0.5 must be two separately-rounded f32 ops
// (numpy semantics); __fmul_rn/__fadd_rn block FMA contraction there.

typedef float f2 __attribute__((ext_vector_type(2)));
typedef float f4 __attribute__((ext_vector_type(4)));

static constexpr uint32_t PRIME1 = 2654435761u;
static constexpr uint32_t PRIME2 = 805459861u;
static constexpr uint32_t HASH_MASK = (1u << 19) - 1u;

__constant__ uint32_t c_offs[16] = {
    0u, 4920u, 40864u, 315496u, 839784u, 1364072u, 1888360u, 2412648u,
    2936936u, 3461224u, 3985512u, 4509800u, 5034088u, 5558376u,
    6082664u, 6606952u};

__global__ __launch_bounds__(256) void gather_kernel(
    const float* __restrict__ inputs,      // [B,3]
    const float* __restrict__ embeddings,  // [4920,2] (level-0 rows)
    const float* __restrict__ table,       // [TOTAL-4920,2]
    float2* __restrict__ dst,              // staged: ws[l*B + b] ; direct: out_f2[b*16 + l]
    int B, int chunks, int directOut)
{
    // --- block -> (level, chunk) with XCD pinning ---
    const int j   = blockIdx.x;
    const int xcd = j & 7;
    const int s   = j >> 3;
    const int lvl = 2 * xcd + (s >= chunks ? 1 : 0);
    const int chunk = (s >= chunks) ? (s - chunks) : s;
    const int base  = chunk * 1024;           // 4 points/thread * 256 threads
    const int tid   = threadIdx.x;

    // --- stage this chunk's inputs through LDS (coalesced, nontemporal) ---
    __shared__ float sIn[3072];
    {
        const float* gp = inputs + (size_t)base * 3;
        const int lim = B * 3 - base * 3;
#pragma unroll
        for (int k = 0; k < 12; ++k) {
            const int i = tid + k * 256;
            sIn[i] = (i < lim) ? __builtin_nontemporal_load(gp + i) : 0.0f;
        }
    }
    __syncthreads();

    // --- level-dependent constants (block-uniform) ---
    const float scale = (float)((16u << lvl) - 1u);   // exactly representable
    const uint32_t off = c_offs[lvl];
    const f2* __restrict__ tb = (lvl == 0)
        ? (const f2*)embeddings
        : ((const f2*)table) + (off - 4920u);
    const bool dense = (lvl < 3);
    const uint32_t dstr  = (16u << lvl) + 1u;   // dense row stride
    const uint32_t dstr2 = dstr * dstr;

    uint32_t idx[4][8];
    float fx[4], fy[4], fz[4];

#pragma unroll
    for (int p = 0; p < 4; ++p) {
        const int li = p * 256 + tid;           // local point index
        // bound=1: x01=(x+1)/2 (add rounds once, *0.5 exact)
        const float x01 = __fadd_rn(sIn[li * 3 + 0], 1.0f) * 0.5f;
        const float y01 = __fadd_rn(sIn[li * 3 + 1], 1.0f) * 0.5f;
        const float z01 = __fadd_rn(sIn[li * 3 + 2], 1.0f) * 0.5f;

        // pos = x01*scale + 0.5 : two separately-rounded ops (NO fma)
        const float px = __fadd_rn(__fmul_rn(x01, scale), 0.5f);
        const float py = __fadd_rn(__fmul_rn(y01, scale), 0.5f);
        const float pz = __fadd_rn(__fmul_rn(z01, scale), 0.5f);

        const float fxf = floorf(px), fyf = floorf(py), fzf = floorf(pz);
        fx[p] = px - fxf;  fy[p] = py - fyf;  fz[p] = pz - fzf;   // exact
        const uint32_t ix = (uint32_t)fxf, iy = (uint32_t)fyf, iz = (uint32_t)fzf;

        if (dense) {
            const uint32_t oy0 = iy * dstr,  oy1 = oy0 + dstr;
            const uint32_t oz0 = iz * dstr2, oz1 = oz0 + dstr2;
            idx[p][0] = ix + oy0 + oz0;  idx[p][1] = idx[p][0] + 1u;
            idx[p][2] = ix + oy1 + oz0;  idx[p][3] = idx[p][2] + 1u;
            idx[p][4] = ix + oy0 + oz1;  idx[p][5] = idx[p][4] + 1u;
            idx[p][6] = ix + oy1 + oz1;  idx[p][7] = idx[p][6] + 1u;
        } else {
            const uint32_t hy0 = iy * PRIME1, hy1 = hy0 + PRIME1;  // u32 wrap
            const uint32_t hz0 = iz * PRIME2, hz1 = hz0 + PRIME2;
            const uint32_t a00 = hy0 ^ hz0, a10 = hy1 ^ hz0;
            const uint32_t a01 = hy0 ^ hz1, a11 = hy1 ^ hz1;
            idx[p][0] = (ix ^ a00) & HASH_MASK;  idx[p][1] = ((ix + 1u) ^ a00) & HASH_MASK;
            idx[p][2] = (ix ^ a10) & HASH_MASK;  idx[p][3] = ((ix + 1u) ^ a10) & HASH_MASK;
            idx[p][4] = (ix ^ a01) & HASH_MASK;  idx[p][5] = ((ix + 1u) ^ a01) & HASH_MASK;
            idx[p][6] = (ix ^ a11) & HASH_MASK;  idx[p][7] = ((ix + 1u) ^ a11) & HASH_MASK;
        }
    }

    // --- issue ALL 32 gathers with per-load keep-alive asms.
    //     asm volatile("" :: "v"(x)) is an opaque immediate USE of each
    //     result: IR sinking cannot move a load past its own use, and all
    //     32 results are forced live => the cluster stays 32-deep.
    //     sched_barrier(0) then stops the MIR scheduler hoisting the
    //     combine loop back into the load block. ---
    f2 e[4][8];
#pragma unroll
    for (int p = 0; p < 4; ++p)
#pragma unroll
        for (int c = 0; c < 8; ++c) {
            e[p][c] = tb[idx[p][c]];
            asm volatile("" :: "v"(e[p][c]));
        }
    __builtin_amdgcn_sched_barrier(0);

    // --- weights (VALU, independent of loads), then combine + write ---
#pragma unroll
    for (int p = 0; p < 4; ++p) {
        const int b = base + p * 256 + tid;
        if (b >= B) continue;
        const float tx = fx[p], ty = fy[p], tz = fz[p];
        const float wx0 = 1.0f - tx, wy0 = 1.0f - ty, wz0 = 1.0f - tz;
        // ((x)*(y))*(z) product order matches jnp.prod
        const float wxy00 = __fmul_rn(wx0, wy0), wxy10 = __fmul_rn(tx, wy0);
        const float wxy01 = __fmul_rn(wx0, ty),  wxy11 = __fmul_rn(tx, ty);
        float w[8];
        w[0] = __fmul_rn(wxy00, wz0); w[1] = __fmul_rn(wxy10, wz0);
        w[2] = __fmul_rn(wxy01, wz0); w[3] = __fmul_rn(wxy11, wz0);
        w[4] = __fmul_rn(wxy00, tz);  w[5] = __fmul_rn(wxy10, tz);
        w[6] = __fmul_rn(wxy01, tz);  w[7] = __fmul_rn(wxy11, tz);

        float r0 = __fmul_rn(w[0], e[p][0].x);
        float r1 = __fmul_rn(w[0], e[p][0].y);
#pragma unroll
        for (int c = 1; c < 8; ++c) {
            r0 = fmaf(w[c], e[p][c].x, r0);
            r1 = fmaf(w[c], e[p][c].y, r1);
        }
        f2 res = {r0, r1};
        if (directOut) {
            __builtin_nontemporal_store(res, (f2*)&dst[(size_t)b * 16 + lvl]);
        } else {
            __builtin_nontemporal_store(res, (f2*)&dst[(size_t)lvl * B + b]);
        }
    }
}

// ws[16][B] float2 (level-major)  ->  out[B][32] float (point-major)
// 256-point tile (36.9KB LDS -> 4 blocks/CU), 8 pinned float4 NT loads per
// thread (depth vs ~900cy HBM latency), XOR-swizzled LDS:
//   logical float2-cell c2=l of row r stored at c2' = l ^ ((r>>1)&15),
//   row stride 36 floats (144B, 16B-aligned). Read side fetches the
//   aligned float4 containing cells {2j,2j+1}; halves swapped when (q&1)
//   because odd XOR keys flip bit0 of the cell index.
__global__ __launch_bounds__(256) void transpose_kernel(
    const float2* __restrict__ ws, float* __restrict__ out, int B)
{
    __shared__ float sT[256 * 36];   // 36864 B -> 4 blocks/CU
    const int tid = threadIdx.x;
    const int b0  = blockIdx.x * 256;
    const bool full = (b0 + 256 <= B);

    f4 v[8];
#pragma unroll
    for (int k = 0; k < 8; ++k) {
        const int idx = k * 256 + tid;   // 0..2047
        const int l   = idx >> 7;        // level 0..15 (wave-uniform)
        const int q   = idx & 127;       // point-pair 0..127
        const int b   = b0 + 2 * q;
        f4 t = {0.f, 0.f, 0.f, 0.f};
        if (full) {
            t = __builtin_nontemporal_load((const f4*)&ws[(size_t)l * B + b]);
        } else {
            if (b < B)     { float2 u = ws[(size_t)l * B + b];     t.x = u.x; t.y = u.y; }
            if (b + 1 < B) { float2 u = ws[(size_t)l * B + b + 1]; t.z = u.x; t.w = u.y; }
        }
        v[k] = t;
        asm volatile("" :: "v"(v[k]));   // pin: all 8 loads in flight
    }
    __builtin_amdgcn_sched_barrier(0);

#pragma unroll
    for (int k = 0; k < 8; ++k) {
        const int idx = k * 256 + tid;
        const int l   = idx >> 7;
        const int q   = idx & 127;
        const int c2  = l ^ (q & 15);    // swizzled float2-cell
        *(float2*)&sT[(2 * q)     * 36 + 2 * c2] = make_float2(v[k].x, v[k].y);
        *(float2*)&sT[(2 * q + 1) * 36 + 2 * c2] = make_float2(v[k].z, v[k].w);
    }
    __syncthreads();

    float* obase = out + (size_t)b0 * 32;
    const int lim4 = (B - b0) * 8;       // valid float4 chunks in this tile
#pragma unroll
    for (int k = 0; k < 8; ++k) {
        const int f = k * 256 + tid;     // 0..2047
        if (f >= lim4) continue;
        const int p = f >> 3;            // point 0..255
        const int jj = f & 7;            // output float4 chunk 0..7
        const int q = p >> 1;
        const int y = (2 * jj) ^ (q & 15);
        const f4 t = *(const f4*)&sT[p * 36 + 2 * (y & ~1)];
        f4 r = (q & 1) ? (f4){t.z, t.w, t.x, t.y} : t;
        __builtin_nontemporal_store(r, (f4*)(obase + (size_t)f * 4));
    }
}

extern "C" void kernel_launch(void* const* d_in, const int* in_sizes, int n_in,
                              void* d_out, int out_size, void* d_ws, size_t ws_size,
                              hipStream_t stream) {
    const float* inputs     = (const float*)d_in[0];
    const float* embeddings = (const float*)d_in[1];
    const float* table      = (const float*)d_in[2];
    float* out              = (float*)d_out;

    const int B = in_sizes[0] / 3;
    const int chunks = (B + 1023) / 1024;
    const size_t need = (size_t)16 * (size_t)B * sizeof(float2);
    const bool staged = ws_size >= need;

    gather_kernel<<<16 * chunks, 256, 0, stream>>>(
        inputs, embeddings, table,
        staged ? (float2*)d_ws : (float2*)d_out,
        B, chunks, staged ? 0 : 1);

    if (staged) {
        transpose_kernel<<<(B + 255) / 256, 256, 0, stream>>>(
            (const float2*)d_ws, out, B);
    }
}

// Round 3
// 1257.772 us; speedup vs baseline: 1.2749x; 1.2749x over previous
//
#include <hip/hip_runtime.h>
#include <cstdint>

// Instant-NGP hash-grid encoder, D=3, L=16, C=2, H=16, PS=2, T=2^19.
// Round-5: fix the load-cluster pin.
//   r4 evidence: per-load asm volatile("" :: "v"(x)) keep-alives SERIALIZED
//   the gathers (each asm forces s_waitcnt vmcnt(0) for its operand before
//   the next load issues) -> 920 -> 1293us, VALUBusy 9.6 -> 6.0, VGPR 60.
//   r4 win kept: nontemporal streaming (inputs/ws/out) cut FETCH_SIZE
//   794 -> 355 MB (table keeps L2 residency).
//   Correct pin: ONE asm volatile("" ::: "memory") AFTER all 32 loads.
//   Memory clobber = wall no load can sink below / no consumer can hoist
//   above, but it consumes no results so it forces no waitcnt itself.
//   Loads issue back-to-back, 64 result VGPRs live across the wall
//   (VGPR_Count >= 110 is the proof), s_waitcnt pass drains vmcnt(31..0)
//   at first use = staged MLP. Same construct in transpose (8x float4).
// NUMERICS: pos = x01*scale + 0.5 must be two separately-rounded f32 ops
// (numpy semantics); __fmul_rn/__fadd_rn block FMA contraction there.

typedef float f2 __attribute__((ext_vector_type(2)));
typedef float f4 __attribute__((ext_vector_type(4)));

static constexpr uint32_t PRIME1 = 2654435761u;
static constexpr uint32_t PRIME2 = 805459861u;
static constexpr uint32_t HASH_MASK = (1u << 19) - 1u;

__constant__ uint32_t c_offs[16] = {
    0u, 4920u, 40864u, 315496u, 839784u, 1364072u, 1888360u, 2412648u,
    2936936u, 3461224u, 3985512u, 4509800u, 5034088u, 5558376u,
    6082664u, 6606952u};

__global__ __launch_bounds__(256) void gather_kernel(
    const float* __restrict__ inputs,      // [B,3]
    const float* __restrict__ embeddings,  // [4920,2] (level-0 rows)
    const float* __restrict__ table,       // [TOTAL-4920,2]
    float2* __restrict__ dst,              // staged: ws[l*B + b] ; direct: out_f2[b*16 + l]
    int B, int chunks, int directOut)
{
    // --- block -> (level, chunk) with XCD pinning ---
    const int j   = blockIdx.x;
    const int xcd = j & 7;
    const int s   = j >> 3;
    const int lvl = 2 * xcd + (s >= chunks ? 1 : 0);
    const int chunk = (s >= chunks) ? (s - chunks) : s;
    const int base  = chunk * 1024;           // 4 points/thread * 256 threads
    const int tid   = threadIdx.x;

    // --- stage this chunk's inputs through LDS (coalesced, nontemporal) ---
    __shared__ float sIn[3072];
    {
        const float* gp = inputs + (size_t)base * 3;
        const int lim = B * 3 - base * 3;
#pragma unroll
        for (int k = 0; k < 12; ++k) {
            const int i = tid + k * 256;
            sIn[i] = (i < lim) ? __builtin_nontemporal_load(gp + i) : 0.0f;
        }
    }
    __syncthreads();

    // --- level-dependent constants (block-uniform) ---
    const float scale = (float)((16u << lvl) - 1u);   // exactly representable
    const uint32_t off = c_offs[lvl];
    const f2* __restrict__ tb = (lvl == 0)
        ? (const f2*)embeddings
        : ((const f2*)table) + (off - 4920u);
    const bool dense = (lvl < 3);
    const uint32_t dstr  = (16u << lvl) + 1u;   // dense row stride
    const uint32_t dstr2 = dstr * dstr;

    uint32_t idx[4][8];
    float fx[4], fy[4], fz[4];

#pragma unroll
    for (int p = 0; p < 4; ++p) {
        const int li = p * 256 + tid;           // local point index
        // bound=1: x01=(x+1)/2 (add rounds once, *0.5 exact)
        const float x01 = __fadd_rn(sIn[li * 3 + 0], 1.0f) * 0.5f;
        const float y01 = __fadd_rn(sIn[li * 3 + 1], 1.0f) * 0.5f;
        const float z01 = __fadd_rn(sIn[li * 3 + 2], 1.0f) * 0.5f;

        // pos = x01*scale + 0.5 : two separately-rounded ops (NO fma)
        const float px = __fadd_rn(__fmul_rn(x01, scale), 0.5f);
        const float py = __fadd_rn(__fmul_rn(y01, scale), 0.5f);
        const float pz = __fadd_rn(__fmul_rn(z01, scale), 0.5f);

        const float fxf = floorf(px), fyf = floorf(py), fzf = floorf(pz);
        fx[p] = px - fxf;  fy[p] = py - fyf;  fz[p] = pz - fzf;   // exact
        const uint32_t ix = (uint32_t)fxf, iy = (uint32_t)fyf, iz = (uint32_t)fzf;

        if (dense) {
            const uint32_t oy0 = iy * dstr,  oy1 = oy0 + dstr;
            const uint32_t oz0 = iz * dstr2, oz1 = oz0 + dstr2;
            idx[p][0] = ix + oy0 + oz0;  idx[p][1] = idx[p][0] + 1u;
            idx[p][2] = ix + oy1 + oz0;  idx[p][3] = idx[p][2] + 1u;
            idx[p][4] = ix + oy0 + oz1;  idx[p][5] = idx[p][4] + 1u;
            idx[p][6] = ix + oy1 + oz1;  idx[p][7] = idx[p][6] + 1u;
        } else {
            const uint32_t hy0 = iy * PRIME1, hy1 = hy0 + PRIME1;  // u32 wrap
            const uint32_t hz0 = iz * PRIME2, hz1 = hz0 + PRIME2;
            const uint32_t a00 = hy0 ^ hz0, a10 = hy1 ^ hz0;
            const uint32_t a01 = hy0 ^ hz1, a11 = hy1 ^ hz1;
            idx[p][0] = (ix ^ a00) & HASH_MASK;  idx[p][1] = ((ix + 1u) ^ a00) & HASH_MASK;
            idx[p][2] = (ix ^ a10) & HASH_MASK;  idx[p][3] = ((ix + 1u) ^ a10) & HASH_MASK;
            idx[p][4] = (ix ^ a01) & HASH_MASK;  idx[p][5] = ((ix + 1u) ^ a01) & HASH_MASK;
            idx[p][6] = (ix ^ a11) & HASH_MASK;  idx[p][7] = ((ix + 1u) ^ a11) & HASH_MASK;
        }
    }

    // --- issue ALL 32 gathers back-to-back, then ONE memory-clobber wall.
    //     No load may sink below the wall (asm may write memory), no
    //     consumer may hoist above it; the wall itself consumes no load
    //     results so it forces no waitcnt -> all 32 stay in flight and
    //     drain vmcnt(31..0) at first use. ---
    f2 e[4][8];
#pragma unroll
    for (int p = 0; p < 4; ++p)
#pragma unroll
        for (int c = 0; c < 8; ++c)
            e[p][c] = tb[idx[p][c]];
    asm volatile("" ::: "memory");
    __builtin_amdgcn_sched_barrier(0);

    // --- weights (VALU, independent of loads), then combine + write ---
#pragma unroll
    for (int p = 0; p < 4; ++p) {
        const int b = base + p * 256 + tid;
        if (b >= B) continue;
        const float tx = fx[p], ty = fy[p], tz = fz[p];
        const float wx0 = 1.0f - tx, wy0 = 1.0f - ty, wz0 = 1.0f - tz;
        // ((x)*(y))*(z) product order matches jnp.prod
        const float wxy00 = __fmul_rn(wx0, wy0), wxy10 = __fmul_rn(tx, wy0);
        const float wxy01 = __fmul_rn(wx0, ty),  wxy11 = __fmul_rn(tx, ty);
        float w[8];
        w[0] = __fmul_rn(wxy00, wz0); w[1] = __fmul_rn(wxy10, wz0);
        w[2] = __fmul_rn(wxy01, wz0); w[3] = __fmul_rn(wxy11, wz0);
        w[4] = __fmul_rn(wxy00, tz);  w[5] = __fmul_rn(wxy10, tz);
        w[6] = __fmul_rn(wxy01, tz);  w[7] = __fmul_rn(wxy11, tz);

        float r0 = __fmul_rn(w[0], e[p][0].x);
        float r1 = __fmul_rn(w[0], e[p][0].y);
#pragma unroll
        for (int c = 1; c < 8; ++c) {
            r0 = fmaf(w[c], e[p][c].x, r0);
            r1 = fmaf(w[c], e[p][c].y, r1);
        }
        f2 res = {r0, r1};
        if (directOut) {
            __builtin_nontemporal_store(res, (f2*)&dst[(size_t)b * 16 + lvl]);
        } else {
            __builtin_nontemporal_store(res, (f2*)&dst[(size_t)lvl * B + b]);
        }
    }
}

// ws[16][B] float2 (level-major)  ->  out[B][32] float (point-major)
// 256-point tile (36.9KB LDS -> 4 blocks/CU), 8 float4 NT loads issued
// back-to-back then one memory-clobber wall (depth 8 vs ~900cy HBM
// latency), XOR-swizzled LDS:
//   logical float2-cell c2=l of row r stored at c2' = l ^ ((r>>1)&15),
//   row stride 36 floats (144B, 16B-aligned). Read side fetches the
//   aligned float4 containing cells {2j,2j+1}; halves swapped when (q&1)
//   because odd XOR keys flip bit0 of the cell index.
__global__ __launch_bounds__(256) void transpose_kernel(
    const float2* __restrict__ ws, float* __restrict__ out, int B)
{
    __shared__ float sT[256 * 36];   // 36864 B -> 4 blocks/CU
    const int tid = threadIdx.x;
    const int b0  = blockIdx.x * 256;
    const bool full = (b0 + 256 <= B);

    f4 v[8];
#pragma unroll
    for (int k = 0; k < 8; ++k) {
        const int idx = k * 256 + tid;   // 0..2047
        const int l   = idx >> 7;        // level 0..15 (wave-uniform)
        const int q   = idx & 127;       // point-pair 0..127
        const int b   = b0 + 2 * q;
        f4 t = {0.f, 0.f, 0.f, 0.f};
        if (full) {
            t = __builtin_nontemporal_load((const f4*)&ws[(size_t)l * B + b]);
        } else {
            if (b < B)     { float2 u = ws[(size_t)l * B + b];     t.x = u.x; t.y = u.y; }
            if (b + 1 < B) { float2 u = ws[(size_t)l * B + b + 1]; t.z = u.x; t.w = u.y; }
        }
        v[k] = t;
    }
    asm volatile("" ::: "memory");   // wall: all 8 loads in flight
    __builtin_amdgcn_sched_barrier(0);

#pragma unroll
    for (int k = 0; k < 8; ++k) {
        const int idx = k * 256 + tid;
        const int l   = idx >> 7;
        const int q   = idx & 127;
        const int c2  = l ^ (q & 15);    // swizzled float2-cell
        *(float2*)&sT[(2 * q)     * 36 + 2 * c2] = make_float2(v[k].x, v[k].y);
        *(float2*)&sT[(2 * q + 1) * 36 + 2 * c2] = make_float2(v[k].z, v[k].w);
    }
    __syncthreads();

    float* obase = out + (size_t)b0 * 32;
    const int lim4 = (B - b0) * 8;       // valid float4 chunks in this tile
#pragma unroll
    for (int k = 0; k < 8; ++k) {
        const int f = k * 256 + tid;     // 0..2047
        if (f >= lim4) continue;
        const int p = f >> 3;            // point 0..255
        const int jj = f & 7;            // output float4 chunk 0..7
        const int q = p >> 1;
        const int y = (2 * jj) ^ (q & 15);
        const f4 t = *(const f4*)&sT[p * 36 + 2 * (y & ~1)];
        f4 r = (q & 1) ? (f4){t.z, t.w, t.x, t.y} : t;
        __builtin_nontemporal_store(r, (f4*)(obase + (size_t)f * 4));
    }
}

extern "C" void kernel_launch(void* const* d_in, const int* in_sizes, int n_in,
                              void* d_out, int out_size, void* d_ws, size_t ws_size,
                              hipStream_t stream) {
    const float* inputs     = (const float*)d_in[0];
    const float* embeddings = (const float*)d_in[1];
    const float* table      = (const float*)d_in[2];
    float* out              = (float*)d_out;

    const int B = in_sizes[0] / 3;
    const int chunks = (B + 1023) / 1024;
    const size_t need = (size_t)16 * (size_t)B * sizeof(float2);
    const bool staged = ws_size >= need;

    gather_kernel<<<16 * chunks, 256, 0, stream>>>(
        inputs, embeddings, table,
        staged ? (float2*)d_ws : (float2*)d_out,
        B, chunks, staged ? 0 : 1);

    if (staged) {
        transpose_kernel<<<(B + 255) / 256, 256, 0, stream>>>(
            (const float2*)d_ws, out, B);
    }
}

// Round 4
// 1171.236 us; speedup vs baseline: 1.3691x; 1.0739x over previous
//
#include <hip/hip_runtime.h>
#include <cstdint>

// Instant-NGP hash-grid encoder, D=3, L=16, C=2, H=16, PS=2, T=2^19.
// Round-6: pair-merged gathers (request-count reduction).
//   Ladder evidence r1-r5: per-wave load depth is NOT the lever
//   (depth 1 -> 8 only 1.4x apart; 3 pin attempts all land at 920us;
//   FETCH 794->425MB moved time <2%). Model: CU-level fill-concurrency /
//   request-path wall: 0.36 line-fills/cyc/CU = C(~80 outstanding)/L(~220cy).
//   Untested lever: REQUEST count. x-corner pairs are always adjacent
//   table entries (dense: idx,idx+1; hashed even-ix: {v, v^1} = one
//   aligned 16B cell because ix+1=ix|1 carries nothing). Merge each pair
//   into one dwordx4: hashed 8->6 requests/point (even-ix lanes 8->4),
//   dense 8->4. If request-limited: ~-25% gather. If fill-limited:
//   neutral -> ceiling declared next round.
//   Kept from r4/r5: nontemporal streaming for inputs/ws/out (table keeps
//   L2 residency; FETCH 794->425MB), XCD level pinning, LDS input stage.
// NUMERICS: pos = x01*scale + 0.5 must be two separately-rounded f32 ops
// (numpy semantics); __fmul_rn/__fadd_rn block FMA contraction there.
// Pair-merge is pure routing (no arithmetic change): absmax must stay
// exactly 4.768e-07.

typedef float f2 __attribute__((ext_vector_type(2)));
typedef float f4 __attribute__((ext_vector_type(4)));
typedef float f4a8 __attribute__((ext_vector_type(4), aligned(8)));

static constexpr uint32_t PRIME1 = 2654435761u;
static constexpr uint32_t PRIME2 = 805459861u;
static constexpr uint32_t HASH_MASK = (1u << 19) - 1u;

__constant__ uint32_t c_offs[16] = {
    0u, 4920u, 40864u, 315496u, 839784u, 1364072u, 1888360u, 2412648u,
    2936936u, 3461224u, 3985512u, 4509800u, 5034088u, 5558376u,
    6082664u, 6606952u};

__global__ __launch_bounds__(256) void gather_kernel(
    const float* __restrict__ inputs,      // [B,3]
    const float* __restrict__ embeddings,  // [4920,2] (level-0 rows)
    const float* __restrict__ table,       // [TOTAL-4920,2]
    float2* __restrict__ dst,              // staged: ws[l*B + b] ; direct: out_f2[b*16 + l]
    int B, int chunks, int directOut)
{
    // --- block -> (level, chunk) with XCD pinning ---
    const int j   = blockIdx.x;
    const int xcd = j & 7;
    const int s   = j >> 3;
    const int lvl = 2 * xcd + (s >= chunks ? 1 : 0);
    const int chunk = (s >= chunks) ? (s - chunks) : s;
    const int base  = chunk * 1024;           // 4 points/thread * 256 threads
    const int tid   = threadIdx.x;

    // --- stage this chunk's inputs through LDS (coalesced, nontemporal) ---
    __shared__ float sIn[3072];
    {
        const float* gp = inputs + (size_t)base * 3;
        const int lim = B * 3 - base * 3;
#pragma unroll
        for (int k = 0; k < 12; ++k) {
            const int i = tid + k * 256;
            sIn[i] = (i < lim) ? __builtin_nontemporal_load(gp + i) : 0.0f;
        }
    }
    __syncthreads();

    // --- level-dependent constants (block-uniform) ---
    const float scale = (float)((16u << lvl) - 1u);   // exactly representable
    const uint32_t off = c_offs[lvl];
    const f2* __restrict__ tb = (lvl == 0)
        ? (const f2*)embeddings
        : ((const f2*)table) + (off - 4920u);
    const float* __restrict__ tbf = (const float*)tb;
    const bool dense = (lvl < 3);
    const uint32_t dstr  = (16u << lvl) + 1u;   // dense row stride
    const uint32_t dstr2 = dstr * dstr;

    f2 e[4][8];
    float fx[4], fy[4], fz[4];

#pragma unroll
    for (int p = 0; p < 4; ++p) {
        const int li = p * 256 + tid;           // local point index
        // bound=1: x01=(x+1)/2 (add rounds once, *0.5 exact)
        const float x01 = __fadd_rn(sIn[li * 3 + 0], 1.0f) * 0.5f;
        const float y01 = __fadd_rn(sIn[li * 3 + 1], 1.0f) * 0.5f;
        const float z01 = __fadd_rn(sIn[li * 3 + 2], 1.0f) * 0.5f;

        // pos = x01*scale + 0.5 : two separately-rounded ops (NO fma)
        const float px = __fadd_rn(__fmul_rn(x01, scale), 0.5f);
        const float py = __fadd_rn(__fmul_rn(y01, scale), 0.5f);
        const float pz = __fadd_rn(__fmul_rn(z01, scale), 0.5f);

        const float fxf = floorf(px), fyf = floorf(py), fzf = floorf(pz);
        fx[p] = px - fxf;  fy[p] = py - fyf;  fz[p] = pz - fzf;   // exact
        const uint32_t ix = (uint32_t)fxf, iy = (uint32_t)fyf, iz = (uint32_t)fzf;

        if (dense) {
            // pairs {i, i+1} always adjacent -> one dwordx4 each (8B-aligned)
            const uint32_t oy0 = iy * dstr,  oy1 = oy0 + dstr;
            const uint32_t oz0 = iz * dstr2, oz1 = oz0 + dstr2;
            const uint32_t i0 = ix + oy0 + oz0, i2 = ix + oy1 + oz0;
            const uint32_t i4 = ix + oy0 + oz1, i6 = ix + oy1 + oz1;
            f4 t0 = *(const f4a8*)(tbf + 2u * i0);
            f4 t2 = *(const f4a8*)(tbf + 2u * i2);
            f4 t4 = *(const f4a8*)(tbf + 2u * i4);
            f4 t6 = *(const f4a8*)(tbf + 2u * i6);
            e[p][0] = (f2){t0.x, t0.y}; e[p][1] = (f2){t0.z, t0.w};
            e[p][2] = (f2){t2.x, t2.y}; e[p][3] = (f2){t2.z, t2.w};
            e[p][4] = (f2){t4.x, t4.y}; e[p][5] = (f2){t4.z, t4.w};
            e[p][6] = (f2){t6.x, t6.y}; e[p][7] = (f2){t6.z, t6.w};
        } else {
            const uint32_t hy0 = iy * PRIME1, hy1 = hy0 + PRIME1;  // u32 wrap
            const uint32_t hz0 = iz * PRIME2, hz1 = hz0 + PRIME2;
            const uint32_t a00 = hy0 ^ hz0, a10 = hy1 ^ hz0;
            const uint32_t a01 = hy0 ^ hz1, a11 = hy1 ^ hz1;
            if (!(ix & 1u)) {
                // ix even: ix+1 = ix|1, so pair = {v, v^1} = aligned 16B cell
                const uint32_t v0 = (ix ^ a00) & HASH_MASK;
                const uint32_t v2 = (ix ^ a10) & HASH_MASK;
                const uint32_t v4 = (ix ^ a01) & HASH_MASK;
                const uint32_t v6 = (ix ^ a11) & HASH_MASK;
                f4 t0 = *(const f4a8*)(tbf + 2u * (v0 & ~1u));
                f4 t2 = *(const f4a8*)(tbf + 2u * (v2 & ~1u));
                f4 t4 = *(const f4a8*)(tbf + 2u * (v4 & ~1u));
                f4 t6 = *(const f4a8*)(tbf + 2u * (v6 & ~1u));
                // route halves by parity of the c0 index
                e[p][0] = (v0 & 1u) ? (f2){t0.z, t0.w} : (f2){t0.x, t0.y};
                e[p][1] = (v0 & 1u) ? (f2){t0.x, t0.y} : (f2){t0.z, t0.w};
                e[p][2] = (v2 & 1u) ? (f2){t2.z, t2.w} : (f2){t2.x, t2.y};
                e[p][3] = (v2 & 1u) ? (f2){t2.x, t2.y} : (f2){t2.z, t2.w};
                e[p][4] = (v4 & 1u) ? (f2){t4.z, t4.w} : (f2){t4.x, t4.y};
                e[p][5] = (v4 & 1u) ? (f2){t4.x, t4.y} : (f2){t4.z, t4.w};
                e[p][6] = (v6 & 1u) ? (f2){t6.z, t6.w} : (f2){t6.x, t6.y};
                e[p][7] = (v6 & 1u) ? (f2){t6.x, t6.y} : (f2){t6.z, t6.w};
            } else {
                // ix odd: ix+1 carries -> second corner is far; 8 separate loads
                const uint32_t ixp = ix + 1u;
                e[p][0] = tb[(ix  ^ a00) & HASH_MASK];
                e[p][1] = tb[(ixp ^ a00) & HASH_MASK];
                e[p][2] = tb[(ix  ^ a10) & HASH_MASK];
                e[p][3] = tb[(ixp ^ a10) & HASH_MASK];
                e[p][4] = tb[(ix  ^ a01) & HASH_MASK];
                e[p][5] = tb[(ixp ^ a01) & HASH_MASK];
                e[p][6] = tb[(ix  ^ a11) & HASH_MASK];
                e[p][7] = tb[(ixp ^ a11) & HASH_MASK];
            }
        }
    }

    // --- weights + combine + write (unchanged arithmetic) ---
#pragma unroll
    for (int p = 0; p < 4; ++p) {
        const int b = base + p * 256 + tid;
        if (b >= B) continue;
        const float tx = fx[p], ty = fy[p], tz = fz[p];
        const float wx0 = 1.0f - tx, wy0 = 1.0f - ty, wz0 = 1.0f - tz;
        // ((x)*(y))*(z) product order matches jnp.prod
        const float wxy00 = __fmul_rn(wx0, wy0), wxy10 = __fmul_rn(tx, wy0);
        const float wxy01 = __fmul_rn(wx0, ty),  wxy11 = __fmul_rn(tx, ty);
        float w[8];
        w[0] = __fmul_rn(wxy00, wz0); w[1] = __fmul_rn(wxy10, wz0);
        w[2] = __fmul_rn(wxy01, wz0); w[3] = __fmul_rn(wxy11, wz0);
        w[4] = __fmul_rn(wxy00, tz);  w[5] = __fmul_rn(wxy10, tz);
        w[6] = __fmul_rn(wxy01, tz);  w[7] = __fmul_rn(wxy11, tz);

        float r0 = __fmul_rn(w[0], e[p][0].x);
        float r1 = __fmul_rn(w[0], e[p][0].y);
#pragma unroll
        for (int c = 1; c < 8; ++c) {
            r0 = fmaf(w[c], e[p][c].x, r0);
            r1 = fmaf(w[c], e[p][c].y, r1);
        }
        f2 res = {r0, r1};
        if (directOut) {
            __builtin_nontemporal_store(res, (f2*)&dst[(size_t)b * 16 + lvl]);
        } else {
            __builtin_nontemporal_store(res, (f2*)&dst[(size_t)lvl * B + b]);
        }
    }
}

// ws[16][B] float2 (level-major)  ->  out[B][32] float (point-major)
// Unchanged from r5 (337us plateau; revisit only after gather resolves).
__global__ __launch_bounds__(256) void transpose_kernel(
    const float2* __restrict__ ws, float* __restrict__ out, int B)
{
    __shared__ float sT[256 * 36];   // 36864 B -> 4 blocks/CU
    const int tid = threadIdx.x;
    const int b0  = blockIdx.x * 256;
    const bool full = (b0 + 256 <= B);

    f4 v[8];
#pragma unroll
    for (int k = 0; k < 8; ++k) {
        const int idx = k * 256 + tid;   // 0..2047
        const int l   = idx >> 7;        // level 0..15 (wave-uniform)
        const int q   = idx & 127;       // point-pair 0..127
        const int b   = b0 + 2 * q;
        f4 t = {0.f, 0.f, 0.f, 0.f};
        if (full) {
            t = __builtin_nontemporal_load((const f4*)&ws[(size_t)l * B + b]);
        } else {
            if (b < B)     { float2 u = ws[(size_t)l * B + b];     t.x = u.x; t.y = u.y; }
            if (b + 1 < B) { float2 u = ws[(size_t)l * B + b + 1]; t.z = u.x; t.w = u.y; }
        }
        v[k] = t;
    }

#pragma unroll
    for (int k = 0; k < 8; ++k) {
        const int idx = k * 256 + tid;
        const int l   = idx >> 7;
        const int q   = idx & 127;
        const int c2  = l ^ (q & 15);    // swizzled float2-cell
        *(float2*)&sT[(2 * q)     * 36 + 2 * c2] = make_float2(v[k].x, v[k].y);
        *(float2*)&sT[(2 * q + 1) * 36 + 2 * c2] = make_float2(v[k].z, v[k].w);
    }
    __syncthreads();

    float* obase = out + (size_t)b0 * 32;
    const int lim4 = (B - b0) * 8;       // valid float4 chunks in this tile
#pragma unroll
    for (int k = 0; k < 8; ++k) {
        const int f = k * 256 + tid;     // 0..2047
        if (f >= lim4) continue;
        const int p = f >> 3;            // point 0..255
        const int jj = f & 7;            // output float4 chunk 0..7
        const int q = p >> 1;
        const int y = (2 * jj) ^ (q & 15);
        const f4 t = *(const f4*)&sT[p * 36 + 2 * (y & ~1)];
        f4 r = (q & 1) ? (f4){t.z, t.w, t.x, t.y} : t;
        __builtin_nontemporal_store(r, (f4*)(obase + (size_t)f * 4));
    }
}

extern "C" void kernel_launch(void* const* d_in, const int* in_sizes, int n_in,
                              void* d_out, int out_size, void* d_ws, size_t ws_size,
                              hipStream_t stream) {
    const float* inputs     = (const float*)d_in[0];
    const float* embeddings = (const float*)d_in[1];
    const float* table      = (const float*)d_in[2];
    float* out              = (float*)d_out;

    const int B = in_sizes[0] / 3;
    const int chunks = (B + 1023) / 1024;
    const size_t need = (size_t)16 * (size_t)B * sizeof(float2);
    const bool staged = ws_size >= need;

    gather_kernel<<<16 * chunks, 256, 0, stream>>>(
        inputs, embeddings, table,
        staged ? (float2*)d_ws : (float2*)d_out,
        B, chunks, staged ? 0 : 1);

    if (staged) {
        transpose_kernel<<<(B + 255) / 256, 256, 0, stream>>>(
            (const float2*)d_ws, out, B);
    }
}